// Round 1
// baseline (3507.047 us; speedup 1.0000x reference)
//
#include <hip/hip_runtime.h>
#include <math.h>

// Problem constants: B=16, T=64, V=50257, E=512, H=1024, L=2
#define Bc 16
#define Tc 64
#define Vc 50257
#define Ec 512
#define Hc 1024

__device__ __forceinline__ float dot4(float4 a, float4 b) {
    return a.x * b.x + a.y * b.y + a.z * b.z + a.w * b.w;
}
__device__ __forceinline__ float sigm(float x) { return 1.0f / (1.0f + expf(-x)); }

// ---------------------------------------------------------------------------
// Build X0 (T*B, 2E) : row m = t*B+b ; cols [0,512)=emb[helper[b,t]], [512,1024)=init[b]
// ---------------------------------------------------------------------------
__global__ __launch_bounds__(256) void build_x0(const float* __restrict__ emb,
                                                const int* __restrict__ helper,
                                                const float* __restrict__ init,
                                                float* __restrict__ X0) {
    int idx = blockIdx.x * 256 + threadIdx.x;
    const int total = Tc * Bc * 1024;  // 1M
    for (int i = idx; i < total; i += gridDim.x * 256) {
        int m = i >> 10;
        int c = i & 1023;
        int t = m >> 4;
        int b = m & 15;
        float v;
        if (c < 512) {
            int w = helper[b * Tc + t];
            v = emb[(size_t)w * Ec + c];
        } else {
            v = init[b * Ec + (c - 512)];
        }
        X0[i] = v;
    }
}

// ---------------------------------------------------------------------------
// h0 one-step GRU with zero initial state.
// xin: input rows per batch; dup=1 -> row is [init[b]; init[b]] (len 1024 from 512)
// writes h0out (B, H)
// grid 64 = 16 b * 4 hseg, block 256
// ---------------------------------------------------------------------------
__global__ __launch_bounds__(256) void h0_layer(const float* __restrict__ xin,
                                                const float* __restrict__ Wih,
                                                const float* __restrict__ bih,
                                                const float* __restrict__ bhh,
                                                float* __restrict__ h0out, int dup) {
    __shared__ float xs[1024];
    int b = blockIdx.x >> 2;
    int hseg = blockIdx.x & 3;
    int tid = threadIdx.x;
    for (int i = tid; i < 1024; i += 256)
        xs[i] = dup ? xin[b * 512 + (i & 511)] : xin[b * 1024 + i];
    __syncthreads();
    int hidx = hseg * 256 + tid;
    const float* wr = Wih + (size_t)hidx * 1024;
    const float* wz = Wih + (size_t)(Hc + hidx) * 1024;
    const float* wn = Wih + (size_t)(2 * Hc + hidx) * 1024;
    float ar = 0.f, az = 0.f, an = 0.f;
    for (int k = 0; k < 1024; k += 4) {
        float4 x4 = *(const float4*)&xs[k];
        ar += dot4(*(const float4*)&wr[k], x4);
        az += dot4(*(const float4*)&wz[k], x4);
        an += dot4(*(const float4*)&wn[k], x4);
    }
    float xr = ar + bih[hidx];
    float xz = az + bih[Hc + hidx];
    float xn = an + bih[2 * Hc + hidx];
    float r = sigm(xr + bhh[hidx]);
    float z = sigm(xz + bhh[Hc + hidx]);
    float n = tanhf(xn + r * bhh[2 * Hc + hidx]);
    h0out[b * Hc + hidx] = (1.f - z) * n;  // h_old = 0
}

// ---------------------------------------------------------------------------
// One GRU scan step (one layer). xp = precomputed input gates (T*B, 3H).
// grid 512 blocks (2 h-indices each), block 256 = 16 batches x 16 k-segments.
// h_in/h_out are ping-pong (B,H) state buffers; ys row m = t*B+b gets h_new.
// ---------------------------------------------------------------------------
__global__ __launch_bounds__(256) void gru_step(const float* __restrict__ xp,
                                                const float* __restrict__ Whh,
                                                const float* __restrict__ bhh,
                                                const float* __restrict__ h_in,
                                                float* __restrict__ h_out,
                                                float* __restrict__ ys, int t) {
    __shared__ float redS[6 * 256];
    int tid = threadIdx.x;
    int b = tid & 15;
    int kseg = tid >> 4;        // 0..15, 64 floats each
    int h0b = blockIdx.x * 2;   // 2 h-indices per block

    // hold this thread's h slice in registers (64 floats)
    float4 hv[16];
    const float4* hp = (const float4*)(h_in + b * Hc + kseg * 64);
#pragma unroll
    for (int i = 0; i < 16; ++i) hv[i] = hp[i];

#pragma unroll
    for (int hl = 0; hl < 2; ++hl) {
        int g = h0b + hl;
        const float4* wr = (const float4*)(Whh + (size_t)g * Hc + kseg * 64);
        const float4* wz = (const float4*)(Whh + (size_t)(Hc + g) * Hc + kseg * 64);
        const float4* wn = (const float4*)(Whh + (size_t)(2 * Hc + g) * Hc + kseg * 64);
        float ar = 0.f, az = 0.f, an = 0.f;
#pragma unroll
        for (int i = 0; i < 16; ++i) {
            float4 h4 = hv[i];
            ar += dot4(wr[i], h4);
            az += dot4(wz[i], h4);
            an += dot4(wn[i], h4);
        }
        redS[(hl * 3 + 0) * 256 + tid] = ar;
        redS[(hl * 3 + 1) * 256 + tid] = az;
        redS[(hl * 3 + 2) * 256 + tid] = an;
    }
    __syncthreads();
    if (tid < 32) {
        int hl = tid >> 4;
        int bb = tid & 15;
        float s0 = 0.f, s1 = 0.f, s2 = 0.f;
        for (int ks = 0; ks < 16; ++ks) {
            s0 += redS[(hl * 3 + 0) * 256 + ks * 16 + bb];
            s1 += redS[(hl * 3 + 1) * 256 + ks * 16 + bb];
            s2 += redS[(hl * 3 + 2) * 256 + ks * 16 + bb];
        }
        int gi = h0b + hl;
        int m = t * Bc + bb;
        const float* xrow = xp + (size_t)m * (3 * Hc);
        float r = sigm(xrow[gi] + s0 + bhh[gi]);
        float z = sigm(xrow[Hc + gi] + s1 + bhh[Hc + gi]);
        float n = tanhf(xrow[2 * Hc + gi] + r * (s2 + bhh[2 * Hc + gi]));
        float hold = h_in[bb * Hc + gi];
        float hnew = (1.f - z) * n + z * hold;
        h_out[bb * Hc + gi] = hnew;
        ys[(size_t)m * Hc + gi] = hnew;
    }
}

// ---------------------------------------------------------------------------
// Generic fp32 NT GEMM: C[m,n] = act(sum_k A[m,k]*Bm[n,k] + bias[n])
// A: (M,K) row-major, Bm: (N,K) row-major. 128x128 tile, BK=16, 8x8/thread.
// remap=1: output row m=t*B+b is stored at row b*T+t (for (B,T,V) logits).
// M must be a multiple of 128; K a multiple of 16; N edge-guarded.
// ---------------------------------------------------------------------------
__global__ __launch_bounds__(256) void gemm_nt(const float* __restrict__ A,
                                               const float* __restrict__ Bm,
                                               const float* __restrict__ bias,
                                               float* __restrict__ C, int M, int N,
                                               int K, int ldc, int act, int remap) {
    __shared__ float As[16][132];
    __shared__ float Bs[16][132];
    int tid = threadIdx.x;
    int m0 = blockIdx.y * 128;
    int n0 = blockIdx.x * 128;
    int nt = tid & 15;   // n-direction (fast for coalesced stores)
    int mt = tid >> 4;   // m-direction
    float acc[8][8];
#pragma unroll
    for (int i = 0; i < 8; ++i)
#pragma unroll
        for (int j = 0; j < 8; ++j) acc[i][j] = 0.f;

    for (int kt = 0; kt < K; kt += 16) {
#pragma unroll
        for (int it = 0; it < 2; ++it) {
            int idx = tid + it * 256;      // 0..511
            int row = idx >> 2;            // 0..127
            int q = idx & 3;               // float4 within the 16-wide k tile
            float4 va = *(const float4*)&A[(size_t)(m0 + row) * K + kt + q * 4];
            As[q * 4 + 0][row] = va.x;
            As[q * 4 + 1][row] = va.y;
            As[q * 4 + 2][row] = va.z;
            As[q * 4 + 3][row] = va.w;
            int brow = n0 + row;
            float4 vb = make_float4(0.f, 0.f, 0.f, 0.f);
            if (brow < N) vb = *(const float4*)&Bm[(size_t)brow * K + kt + q * 4];
            Bs[q * 4 + 0][row] = vb.x;
            Bs[q * 4 + 1][row] = vb.y;
            Bs[q * 4 + 2][row] = vb.z;
            Bs[q * 4 + 3][row] = vb.w;
        }
        __syncthreads();
#pragma unroll
        for (int kk = 0; kk < 16; ++kk) {
            float4 a0 = *(const float4*)&As[kk][mt * 8];
            float4 a1 = *(const float4*)&As[kk][mt * 8 + 4];
            float4 b0 = *(const float4*)&Bs[kk][nt * 8];
            float4 b1 = *(const float4*)&Bs[kk][nt * 8 + 4];
            float av[8] = {a0.x, a0.y, a0.z, a0.w, a1.x, a1.y, a1.z, a1.w};
            float bv[8] = {b0.x, b0.y, b0.z, b0.w, b1.x, b1.y, b1.z, b1.w};
#pragma unroll
            for (int i = 0; i < 8; ++i)
#pragma unroll
                for (int j = 0; j < 8; ++j) acc[i][j] += av[i] * bv[j];
        }
        __syncthreads();
    }

    float bv[8];
#pragma unroll
    for (int j = 0; j < 8; ++j) {
        int n = n0 + nt * 8 + j;
        bv[j] = (bias != nullptr && n < N) ? bias[n] : 0.f;
    }
    bool edge = (n0 + 128 > N);
    bool vec4 = (!edge) && ((ldc & 3) == 0);
#pragma unroll
    for (int i = 0; i < 8; ++i) {
        int m = m0 + mt * 8 + i;
        int orow = remap ? ((m & 15) * Tc + (m >> 4)) : m;
        float* crow = C + (size_t)orow * ldc + n0 + nt * 8;
        float v[8];
#pragma unroll
        for (int j = 0; j < 8; ++j) {
            float x = acc[i][j] + bv[j];
            v[j] = act ? tanhf(x) : x;
        }
        if (vec4) {
            *(float4*)&crow[0] = make_float4(v[0], v[1], v[2], v[3]);
            *(float4*)&crow[4] = make_float4(v[4], v[5], v[6], v[7]);
        } else {
            for (int j = 0; j < 8; ++j) {
                int n = n0 + nt * 8 + j;
                if (n < N) crow[j] = v[j];
            }
        }
    }
}

// ---------------------------------------------------------------------------
extern "C" void kernel_launch(void* const* d_in, const int* in_sizes, int n_in,
                              void* d_out, int out_size, void* d_ws, size_t ws_size,
                              hipStream_t stream) {
    const float* init  = (const float*)d_in[0];   // (16,512)
    const int*   helper = (const int*)d_in[1];    // (16,64)
    const float* emb   = (const float*)d_in[2];   // (50257,512)
    const float* W_ih0 = (const float*)d_in[3];   // (3072,1024)
    const float* W_hh0 = (const float*)d_in[4];   // (3072,1024)
    const float* b_ih0 = (const float*)d_in[5];
    const float* b_hh0 = (const float*)d_in[6];
    const float* W_ih1 = (const float*)d_in[7];   // (3072,1024)
    const float* W_hh1 = (const float*)d_in[8];   // (3072,1024)
    const float* b_ih1 = (const float*)d_in[9];
    const float* b_hh1 = (const float*)d_in[10];
    const float* Wc_w  = (const float*)d_in[11];  // (512,1024)
    const float* Wc_b  = (const float*)d_in[12];
    float* out = (float*)d_out;                   // (16,64,50257)

    float* ws  = (float*)d_ws;
    float* X0  = ws;                    // 1,048,576
    float* xp0 = X0 + (1 << 20);        // 3,145,728
    float* ys0 = xp0 + 3 * (1 << 20);   // 1,048,576
    float* xp1 = ys0 + (1 << 20);       // 3,145,728
    float* ys1 = xp1 + 3 * (1 << 20);   // 1,048,576
    float* fin = ys1 + (1 << 20);       // 524,288
    float* hA0 = fin + (1 << 19);       // 16,384 each
    float* hA1 = hA0 + Bc * Hc;
    float* hB0 = hA1 + Bc * Hc;
    float* hB1 = hB0 + Bc * Hc;

    // Phase A: initial hidden states (one GRU step over [init;init], zero state)
    h0_layer<<<64, 256, 0, stream>>>(init, W_ih0, b_ih0, b_hh0, hA0, 1);
    h0_layer<<<64, 256, 0, stream>>>(hA0, W_ih1, b_ih1, b_hh1, hB0, 0);

    // Phase B: decode inputs and input-gate precompute for layer 0
    build_x0<<<1024, 256, 0, stream>>>(emb, helper, init, X0);
    gemm_nt<<<dim3(24, 8), 256, 0, stream>>>(X0, W_ih0, b_ih0, xp0,
                                             1024, 3072, 1024, 3072, 0, 0);
    // layer-0 scan
    for (int t = 0; t < Tc; ++t) {
        const float* hi = (t & 1) ? hA1 : hA0;
        float* ho = (t & 1) ? hA0 : hA1;
        gru_step<<<512, 256, 0, stream>>>(xp0, W_hh0, b_hh0, hi, ho, ys0, t);
    }
    // layer-1 input gates + scan
    gemm_nt<<<dim3(24, 8), 256, 0, stream>>>(ys0, W_ih1, b_ih1, xp1,
                                             1024, 3072, 1024, 3072, 0, 0);
    for (int t = 0; t < Tc; ++t) {
        const float* hi = (t & 1) ? hB1 : hB0;
        float* ho = (t & 1) ? hB0 : hB1;
        gru_step<<<512, 256, 0, stream>>>(xp1, W_hh1, b_hh1, hi, ho, ys1, t);
    }

    // Phase C: final = tanh(ys1 @ Wc_w^T + Wc_b)   (1024 x 512)
    gemm_nt<<<dim3(4, 8), 256, 0, stream>>>(ys1, Wc_w, Wc_b, fin,
                                            1024, 512, 1024, 512, 1, 0);

    // Phase D: logits = final @ emb^T, stored with (t,b)->(b,t) row remap
    gemm_nt<<<dim3((Vc + 127) / 128, 8), 256, 0, stream>>>(fin, emb, nullptr, out,
                                                           1024, Vc, 512, Vc, 0, 1);
}